// Round 1
// baseline (3425.639 us; speedup 1.0000x reference)
//
#include <hip/hip_runtime.h>

// STGNN K-hop propagation:
//   deg = histogram(col); deg_inv = deg^-0.5 (0 if deg==0)
//   norm[e] = deg_inv[row[e]] * deg_inv[col[e]]
//   hidden = hopwise[0]*x
//   for hop in 0..K-1: x = scatter_add(norm*(x[row]+ef), col); hidden += hopwise[hop+1]*x

__global__ void deg_kernel(const int* __restrict__ col, float* __restrict__ deg, int E) {
    int e = blockIdx.x * blockDim.x + threadIdx.x;
    if (e < E) atomicAdd(&deg[col[e]], 1.0f);
}

__global__ void deginv_kernel(float* __restrict__ deg, int n) {
    int i = blockIdx.x * blockDim.x + threadIdx.x;
    if (i < n) {
        float d = deg[i];
        deg[i] = (d > 0.0f) ? (1.0f / sqrtf(d)) : 0.0f;
    }
}

__global__ void norm_kernel(const int* __restrict__ row, const int* __restrict__ col,
                            const float* __restrict__ deginv, float* __restrict__ norm,
                            int E) {
    int e = blockIdx.x * blockDim.x + threadIdx.x;
    if (e < E) norm[e] = deginv[row[e]] * deginv[col[e]];
}

__global__ void init_out_kernel(const float* __restrict__ x, const float* __restrict__ hopwise,
                                float* __restrict__ out, int n4) {
    int i = blockIdx.x * blockDim.x + threadIdx.x;
    if (i < n4) {
        float h0 = hopwise[0];
        float4 v = ((const float4*)x)[i];
        float4 o;
        o.x = h0 * v.x; o.y = h0 * v.y; o.z = h0 * v.z; o.w = h0 * v.w;
        ((float4*)out)[i] = o;
    }
}

__global__ void axpy_kernel(const float* __restrict__ xh, const float* __restrict__ hopwise,
                            int hop, float* __restrict__ out, int n4) {
    int i = blockIdx.x * blockDim.x + threadIdx.x;
    if (i < n4) {
        float h = hopwise[hop];
        float4 v = ((const float4*)xh)[i];
        float4 o = ((float4*)out)[i];
        o.x += h * v.x; o.y += h * v.y; o.z += h * v.z; o.w += h * v.w;
        ((float4*)out)[i] = o;
    }
}

// One thread per (edge, float4-chunk). chunks = D/4.
__global__ void edge_kernel(const int* __restrict__ row, const int* __restrict__ col,
                            const float* __restrict__ norm,
                            const float* __restrict__ xcur, const float* __restrict__ ef,
                            float* __restrict__ xnext, int E, int chunks) {
    int idx = blockIdx.x * blockDim.x + threadIdx.x;
    int total = E * chunks;
    if (idx >= total) return;
    int e = idx / chunks;
    int c = idx - e * chunks;
    int r  = row[e];
    int cl = col[e];
    float nrm = norm[e];
    float4 xv = ((const float4*)xcur)[(size_t)r * chunks + c];
    float4 ev = ((const float4*)ef)[(size_t)e * chunks + c];
    float4 m;
    m.x = nrm * (xv.x + ev.x);
    m.y = nrm * (xv.y + ev.y);
    m.z = nrm * (xv.z + ev.z);
    m.w = nrm * (xv.w + ev.w);
    float* dst = xnext + ((size_t)cl * chunks + c) * 4;
    atomicAdd(dst + 0, m.x);
    atomicAdd(dst + 1, m.y);
    atomicAdd(dst + 2, m.z);
    atomicAdd(dst + 3, m.w);
}

extern "C" void kernel_launch(void* const* d_in, const int* in_sizes, int n_in,
                              void* d_out, int out_size, void* d_ws, size_t ws_size,
                              hipStream_t stream) {
    const float* x       = (const float*)d_in[0];
    const float* ef      = (const float*)d_in[1];
    const float* hopwise = (const float*)d_in[2];
    const int*   eidx    = (const int*)d_in[3];

    const int E = in_sizes[3] / 2;
    const int D = in_sizes[1] / E;
    const int N = in_sizes[0] / D;
    const int K = in_sizes[2] - 1;
    const int chunks = D / 4;           // D=96 -> 24
    const int ND4 = (N * D) / 4;

    const int* row = eidx;
    const int* col = eidx + E;
    float* out = (float*)d_out;

    // Workspace layout (all float4-aligned: N=50000 -> 200000B, +E*4 -> ok)
    float* deginv = (float*)d_ws;            // N floats (deg, then deg_inv in place)
    float* norm   = deginv + N;              // E floats
    float* buf0   = norm + E;                // N*D floats
    float* buf1   = buf0 + (size_t)N * D;    // N*D floats

    const int BT = 256;

    // 1) degree histogram
    hipMemsetAsync(deginv, 0, (size_t)N * sizeof(float), stream);
    deg_kernel<<<(E + BT - 1) / BT, BT, 0, stream>>>(col, deginv, E);
    // 2) deg -> deg^-0.5
    deginv_kernel<<<(N + BT - 1) / BT, BT, 0, stream>>>(deginv, N);
    // 3) per-edge norm
    norm_kernel<<<(E + BT - 1) / BT, BT, 0, stream>>>(row, col, deginv, norm, E);
    // 4) hidden = hopwise[0] * x
    init_out_kernel<<<(ND4 + BT - 1) / BT, BT, 0, stream>>>(x, hopwise, out, ND4);

    // 5) K hops
    const float* xcur = x;
    for (int hop = 0; hop < K; ++hop) {
        float* xnext = (hop & 1) ? buf1 : buf0;
        hipMemsetAsync(xnext, 0, (size_t)N * D * sizeof(float), stream);
        int total = E * chunks;
        edge_kernel<<<(total + BT - 1) / BT, BT, 0, stream>>>(row, col, norm, xcur, ef,
                                                              xnext, E, chunks);
        axpy_kernel<<<(ND4 + BT - 1) / BT, BT, 0, stream>>>(xnext, hopwise, hop + 1, out, ND4);
        xcur = xnext;
    }
}

// Round 2
// 1094.655 us; speedup vs baseline: 3.1294x; 3.1294x over previous
//
#include <hip/hip_runtime.h>

// STGNN K-hop propagation, CSR-by-destination (no fp32 atomics in hot path):
//   deg = histogram(col); deginv = deg^-0.5
//   norm[e] = deginv[row[e]] * deginv[col[e]]
//   CSR: starts = exscan(deg); eids = edges bucketed by col
//   hidden = hopwise[0]*x
//   per hop: xnext[n,:] = sum_{e in in(n)} norm[e]*(xcur[row[e],:]+ef[e,:])
//            hidden[n,:] += hopwise[hop+1]*xnext[n,:]

__global__ void deg_kernel(const int* __restrict__ col, int* __restrict__ deg, int E) {
    int e = blockIdx.x * blockDim.x + threadIdx.x;
    if (e < E) atomicAdd(&deg[col[e]], 1);
}

__global__ void deginv_kernel(const int* __restrict__ deg, float* __restrict__ deginv, int n) {
    int i = blockIdx.x * blockDim.x + threadIdx.x;
    if (i < n) {
        int d = deg[i];
        deginv[i] = (d > 0) ? rsqrtf((float)d) : 0.0f;
    }
}

// Single-block exclusive scan of deg[0..n) -> starts[0..n], starts[n]=total, cursor=starts.
__global__ __launch_bounds__(1024) void scan_kernel(const int* __restrict__ deg,
                                                    int* __restrict__ starts,
                                                    int* __restrict__ cursor, int n) {
    __shared__ int smem[1024];
    __shared__ int carry_s;
    if (threadIdx.x == 0) carry_s = 0;
    __syncthreads();
    for (int base = 0; base < n; base += 1024) {
        int i = base + (int)threadIdx.x;
        int v = (i < n) ? deg[i] : 0;
        smem[threadIdx.x] = v;
        __syncthreads();
        for (int off = 1; off < 1024; off <<= 1) {
            int t = (threadIdx.x >= (unsigned)off) ? smem[threadIdx.x - off] : 0;
            __syncthreads();
            smem[threadIdx.x] += t;
            __syncthreads();
        }
        int incl = smem[threadIdx.x];
        int excl = incl - v + carry_s;
        if (i < n) { starts[i] = excl; cursor[i] = excl; }
        __syncthreads();
        if (threadIdx.x == 1023) carry_s += smem[1023];
        __syncthreads();
    }
    if (threadIdx.x == 0) starts[n] = carry_s;
}

__global__ void fill_kernel(const int* __restrict__ col, int* __restrict__ cursor,
                            int* __restrict__ eids, int E) {
    int e = blockIdx.x * blockDim.x + threadIdx.x;
    if (e < E) {
        int pos = atomicAdd(&cursor[col[e]], 1);
        eids[pos] = e;
    }
}

__global__ void norm_kernel(const int* __restrict__ row, const int* __restrict__ col,
                            const float* __restrict__ deginv, float* __restrict__ norm,
                            int E) {
    int e = blockIdx.x * blockDim.x + threadIdx.x;
    if (e < E) norm[e] = deginv[row[e]] * deginv[col[e]];
}

__global__ void init_out_kernel(const float* __restrict__ x, const float* __restrict__ hopwise,
                                float* __restrict__ out, int n4) {
    int i = blockIdx.x * blockDim.x + threadIdx.x;
    if (i < n4) {
        float h0 = hopwise[0];
        float4 v = ((const float4*)x)[i];
        float4 o;
        o.x = h0 * v.x; o.y = h0 * v.y; o.z = h0 * v.z; o.w = h0 * v.w;
        ((float4*)out)[i] = o;
    }
}

// One block per node, blockDim = D (96). Thread = feature dim.
// Gathers incoming messages, writes xnext and accumulates into out (fused axpy).
__global__ void hop_kernel(const int* __restrict__ starts, const int* __restrict__ eids,
                           const int* __restrict__ row, const float* __restrict__ norm,
                           const float* __restrict__ xcur, const float* __restrict__ ef,
                           float* __restrict__ xnext, float* __restrict__ out,
                           const float* __restrict__ hopwise, int hop, int D) {
    int node = blockIdx.x;
    int d = threadIdx.x;              // 0..D-1
    int s = starts[node];
    int e_end = starts[node + 1];
    float acc = 0.0f;
    for (int j = s; j < e_end; ++j) {
        int e = eids[j];
        int r = row[e];
        float nm = norm[e];
        acc += nm * (xcur[(size_t)r * D + d] + ef[(size_t)e * D + d]);
    }
    size_t o = (size_t)node * D + d;
    xnext[o] = acc;
    out[o] += hopwise[hop] * acc;
}

extern "C" void kernel_launch(void* const* d_in, const int* in_sizes, int n_in,
                              void* d_out, int out_size, void* d_ws, size_t ws_size,
                              hipStream_t stream) {
    const float* x       = (const float*)d_in[0];
    const float* ef      = (const float*)d_in[1];
    const float* hopwise = (const float*)d_in[2];
    const int*   eidx    = (const int*)d_in[3];

    const int E = in_sizes[3] / 2;
    const int D = in_sizes[1] / E;          // 96
    const int N = in_sizes[0] / D;          // 50000
    const int K = in_sizes[2] - 1;          // 3
    const int ND4 = (N * D) / 4;

    const int* row = eidx;
    const int* col = eidx + E;
    float* out = (float*)d_out;

    // Workspace layout (ints/floats are 4B; everything stays 16B-aligned since
    // N is even and E is a multiple of 4):
    char* w = (char*)d_ws;
    int*   deg    = (int*)w;                 w += (size_t)N * 4;
    int*   starts = (int*)w;                 w += (size_t)(N + 4) * 4;  // N+1, padded
    int*   cursor = (int*)w;                 w += (size_t)N * 4;
    int*   eids   = (int*)w;                 w += (size_t)E * 4;
    float* deginv = (float*)w;               w += (size_t)N * 4;
    float* norm   = (float*)w;               w += (size_t)E * 4;
    float* buf0   = (float*)w;               w += (size_t)N * D * 4;
    float* buf1   = (float*)w;               /* w += N*D*4 */

    const int BT = 256;

    // CSR build + norm
    hipMemsetAsync(deg, 0, (size_t)N * sizeof(int), stream);
    deg_kernel<<<(E + BT - 1) / BT, BT, 0, stream>>>(col, deg, E);
    deginv_kernel<<<(N + BT - 1) / BT, BT, 0, stream>>>(deg, deginv, N);
    scan_kernel<<<1, 1024, 0, stream>>>(deg, starts, cursor, N);
    fill_kernel<<<(E + BT - 1) / BT, BT, 0, stream>>>(col, cursor, eids, E);
    norm_kernel<<<(E + BT - 1) / BT, BT, 0, stream>>>(row, col, deginv, norm, E);

    // hidden = hopwise[0]*x
    init_out_kernel<<<(ND4 + BT - 1) / BT, BT, 0, stream>>>(x, hopwise, out, ND4);

    // K hops, gather-only (no memset needed: hop_kernel overwrites xnext)
    const float* xcur = x;
    for (int hop = 0; hop < K; ++hop) {
        float* xnext = (hop & 1) ? buf1 : buf0;
        hop_kernel<<<N, D, 0, stream>>>(starts, eids, row, norm, xcur, ef,
                                        xnext, out, hopwise, hop + 1, D);
        xcur = xnext;
    }
}

// Round 3
// 734.403 us; speedup vs baseline: 4.6645x; 1.4905x over previous
//
#include <hip/hip_runtime.h>

// STGNN K-hop propagation, CSR-by-destination, hop-invariant edge term hoisted:
//   norm[e] = deginv[row[e]]*deginv[col[e]]
//   b[n,:]  = sum_{e in in(n)} norm[e]*ef[e,:]          (computed ONCE)
//   hidden  = hopwise[0]*x
//   per hop: xnext[n,:] = sum_{e in in(n)} norm[e]*xcur[row[e],:] + b[n,:]
//            hidden += hopwise[hop+1]*xnext
// Slot-ordered edat[j] = (row[e], norm[e]) removes the eids indirection from
// the hop inner loop (one indirect load per edge, unrolled x4).

__global__ void deg_kernel(const int* __restrict__ col, int* __restrict__ deg, int E) {
    int e = blockIdx.x * blockDim.x + threadIdx.x;
    if (e < E) atomicAdd(&deg[col[e]], 1);
}

__global__ void deginv_kernel(const int* __restrict__ deg, float* __restrict__ deginv, int n) {
    int i = blockIdx.x * blockDim.x + threadIdx.x;
    if (i < n) {
        int d = deg[i];
        deginv[i] = (d > 0) ? rsqrtf((float)d) : 0.0f;
    }
}

// ---- hierarchical exclusive scan: 1024 elems/block ----
__global__ __launch_bounds__(256) void scan1_kernel(const int* __restrict__ deg,
                                                    int* __restrict__ starts,
                                                    int* __restrict__ bsums, int n) {
    int t = threadIdx.x;
    int i = blockIdx.x * 1024 + t * 4;
    int4 v = make_int4(0, 0, 0, 0);
    if (i + 3 < n) v = *(const int4*)(deg + i);
    else {
        if (i + 0 < n) v.x = deg[i + 0];
        if (i + 1 < n) v.y = deg[i + 1];
        if (i + 2 < n) v.z = deg[i + 2];
        if (i + 3 < n) v.w = deg[i + 3];
    }
    int s0 = v.x, s1 = s0 + v.y, s2 = s1 + v.z, s3 = s2 + v.w;
    int tot = s3;
    int lane = t & 63;
    int incl = tot;
    for (int off = 1; off < 64; off <<= 1) {
        int u = __shfl_up(incl, off, 64);
        if (lane >= off) incl += u;
    }
    __shared__ int wsum[4];
    __shared__ int woff[4];
    int wid = t >> 6;
    if (lane == 63) wsum[wid] = incl;
    __syncthreads();
    if (t == 0) { int a = 0; for (int w = 0; w < 4; ++w) { woff[w] = a; a += wsum[w]; } }
    __syncthreads();
    int excl = incl - tot + woff[wid];
    if (i + 0 < n) starts[i + 0] = excl;
    if (i + 1 < n) starts[i + 1] = excl + s0;
    if (i + 2 < n) starts[i + 2] = excl + s1;
    if (i + 3 < n) starts[i + 3] = excl + s2;
    if (t == 255) bsums[blockIdx.x] = woff[3] + wsum[3];
}

__global__ __launch_bounds__(64) void scan2_kernel(int* __restrict__ bsums, int nb,
                                                   int* __restrict__ starts, int n, int total) {
    int lane = threadIdx.x;
    int v = (lane < nb) ? bsums[lane] : 0;
    int incl = v;
    for (int off = 1; off < 64; off <<= 1) {
        int u = __shfl_up(incl, off, 64);
        if (lane >= off) incl += u;
    }
    if (lane < nb) bsums[lane] = incl - v;
    if (lane == 0) starts[n] = total;
}

__global__ __launch_bounds__(256) void scan3_kernel(int* __restrict__ starts,
                                                    int* __restrict__ cursor,
                                                    const int* __restrict__ bsums, int n) {
    int t = threadIdx.x;
    int i = blockIdx.x * 1024 + t * 4;
    int off = bsums[blockIdx.x];
    for (int k = 0; k < 4; ++k) {
        int ii = i + k;
        if (ii < n) {
            int s = starts[ii] + off;
            starts[ii] = s;
            cursor[ii] = s;
        }
    }
}

__global__ void fill_kernel(const int* __restrict__ col, int* __restrict__ cursor,
                            int* __restrict__ eids, int E) {
    int e = blockIdx.x * blockDim.x + threadIdx.x;
    if (e < E) {
        int pos = atomicAdd(&cursor[col[e]], 1);
        eids[pos] = e;
    }
}

// edat[j] = (bitcast row[e], norm[e]) in CSR slot order
__global__ void slot_kernel(const int* __restrict__ eids, const int* __restrict__ row,
                            const int* __restrict__ col, const float* __restrict__ deginv,
                            float2* __restrict__ edat, int E) {
    int j = blockIdx.x * blockDim.x + threadIdx.x;
    if (j < E) {
        int e = eids[j];
        int r = row[e], c = col[e];
        float2 o;
        o.x = __int_as_float(r);
        o.y = deginv[r] * deginv[c];
        edat[j] = o;
    }
}

// b[n,d] = sum over in-edges of norm*ef  (one block per node, thread = dim)
__global__ __launch_bounds__(96) void b_kernel(const int* __restrict__ starts,
                                               const int* __restrict__ eids,
                                               const float2* __restrict__ edat,
                                               const float* __restrict__ ef,
                                               float* __restrict__ bvec, int D) {
    int node = blockIdx.x;
    int d = threadIdx.x;
    int s = starts[node], e_end = starts[node + 1];
    float acc = 0.0f;
    int j = s;
    for (; j + 4 <= e_end; j += 4) {
        int e0 = eids[j], e1 = eids[j + 1], e2 = eids[j + 2], e3 = eids[j + 3];
        float n0 = edat[j].y, n1 = edat[j + 1].y, n2 = edat[j + 2].y, n3 = edat[j + 3].y;
        float f0 = ef[(size_t)e0 * D + d];
        float f1 = ef[(size_t)e1 * D + d];
        float f2 = ef[(size_t)e2 * D + d];
        float f3 = ef[(size_t)e3 * D + d];
        acc += n0 * f0 + n1 * f1 + n2 * f2 + n3 * f3;
    }
    for (; j < e_end; ++j) {
        acc += edat[j].y * ef[(size_t)eids[j] * D + d];
    }
    bvec[(size_t)node * D + d] = acc;
}

__global__ void init_out_kernel(const float* __restrict__ x, const float* __restrict__ hopwise,
                                float* __restrict__ out, int n4) {
    int i = blockIdx.x * blockDim.x + threadIdx.x;
    if (i < n4) {
        float h0 = hopwise[0];
        float4 v = ((const float4*)x)[i];
        float4 o;
        o.x = h0 * v.x; o.y = h0 * v.y; o.z = h0 * v.z; o.w = h0 * v.w;
        ((float4*)out)[i] = o;
    }
}

// xnext[n,:] = sum norm*xcur[row] + b[n,:]; out += hopwise[hop]*xnext
__global__ __launch_bounds__(96) void hop_kernel(const int* __restrict__ starts,
                                                 const float2* __restrict__ edat,
                                                 const float* __restrict__ xcur,
                                                 const float* __restrict__ bvec,
                                                 float* __restrict__ xnext,
                                                 float* __restrict__ out,
                                                 const float* __restrict__ hopwise,
                                                 int hop, int D) {
    int node = blockIdx.x;
    int d = threadIdx.x;
    int s = starts[node], e_end = starts[node + 1];
    float acc = 0.0f;
    int j = s;
    for (; j + 4 <= e_end; j += 4) {
        float2 a0 = edat[j], a1 = edat[j + 1], a2 = edat[j + 2], a3 = edat[j + 3];
        int r0 = __float_as_int(a0.x), r1 = __float_as_int(a1.x);
        int r2 = __float_as_int(a2.x), r3 = __float_as_int(a3.x);
        float x0 = xcur[(size_t)r0 * D + d];
        float x1 = xcur[(size_t)r1 * D + d];
        float x2 = xcur[(size_t)r2 * D + d];
        float x3 = xcur[(size_t)r3 * D + d];
        acc += a0.y * x0 + a1.y * x1 + a2.y * x2 + a3.y * x3;
    }
    for (; j < e_end; ++j) {
        float2 a = edat[j];
        acc += a.y * xcur[(size_t)__float_as_int(a.x) * D + d];
    }
    size_t o = (size_t)node * D + d;
    float xv = acc + bvec[o];
    xnext[o] = xv;
    out[o] += hopwise[hop] * xv;
}

extern "C" void kernel_launch(void* const* d_in, const int* in_sizes, int n_in,
                              void* d_out, int out_size, void* d_ws, size_t ws_size,
                              hipStream_t stream) {
    const float* x       = (const float*)d_in[0];
    const float* ef      = (const float*)d_in[1];
    const float* hopwise = (const float*)d_in[2];
    const int*   eidx    = (const int*)d_in[3];

    const int E = in_sizes[3] / 2;
    const int D = in_sizes[1] / E;          // 96
    const int N = in_sizes[0] / D;          // 50000
    const int K = in_sizes[2] - 1;          // 3
    const int ND4 = (N * D) / 4;

    const int* row = eidx;
    const int* col = eidx + E;
    float* out = (float*)d_out;

    // Workspace layout (all offsets multiples of 8 B given N even, E mult of 4)
    char* w = (char*)d_ws;
    int*    deg    = (int*)w;     w += (size_t)N * 4;
    int*    starts = (int*)w;     w += (size_t)(N + 8) * 4;
    int*    cursor = (int*)w;     w += (size_t)N * 4;
    int*    eids   = (int*)w;     w += (size_t)E * 4;
    float*  deginv = (float*)w;   w += (size_t)N * 4;
    int*    bsums  = (int*)w;     w += 256 * 4;
    float2* edat   = (float2*)w;  w += (size_t)E * 8;
    float*  bvec   = (float*)w;   w += (size_t)N * D * 4;
    float*  buf0   = (float*)w;   w += (size_t)N * D * 4;
    float*  buf1   = (float*)w;   /* w += N*D*4 */

    const int BT = 256;
    const int nScanBlocks = (N + 1023) / 1024;   // 49 for N=50000

    // CSR build
    hipMemsetAsync(deg, 0, (size_t)N * sizeof(int), stream);
    deg_kernel<<<(E + BT - 1) / BT, BT, 0, stream>>>(col, deg, E);
    deginv_kernel<<<(N + BT - 1) / BT, BT, 0, stream>>>(deg, deginv, N);
    scan1_kernel<<<nScanBlocks, 256, 0, stream>>>(deg, starts, bsums, N);
    scan2_kernel<<<1, 64, 0, stream>>>(bsums, nScanBlocks, starts, N, E);
    scan3_kernel<<<nScanBlocks, 256, 0, stream>>>(starts, cursor, bsums, N);
    fill_kernel<<<(E + BT - 1) / BT, BT, 0, stream>>>(col, cursor, eids, E);
    slot_kernel<<<(E + BT - 1) / BT, BT, 0, stream>>>(eids, row, col, deginv, edat, E);

    // hop-invariant edge term (reads ef exactly once)
    b_kernel<<<N, D, 0, stream>>>(starts, eids, edat, ef, bvec, D);

    // hidden = hopwise[0]*x
    init_out_kernel<<<(ND4 + BT - 1) / BT, BT, 0, stream>>>(x, hopwise, out, ND4);

    // K hops, gather-only
    const float* xcur = x;
    for (int hop = 0; hop < K; ++hop) {
        float* xnext = (hop & 1) ? buf1 : buf0;
        hop_kernel<<<N, D, 0, stream>>>(starts, edat, xcur, bvec, xnext, out,
                                        hopwise, hop + 1, D);
        xcur = xnext;
    }
}

// Round 4
// 687.310 us; speedup vs baseline: 4.9841x; 1.0685x over previous
//
#include <hip/hip_runtime.h>

// STGNN K-hop propagation, CSR-by-destination, float4 chunked gathers.
//   norm[e] = deginv[row[e]]*deginv[col[e]]
//   b[n,:]  = sum_in norm*ef      (hop-invariant, computed inside fused hop1)
//   hop1 (fused): x1 = S*x + b; out = h0*x + h1*x1; bvec = b
//   hops 2..K:    xk = S*x_{k-1} + b; out += hk*xk
// Thread mapping in hot kernels: global id g -> node = g/24, chunk = g%24,
// each thread owns one float4 (16B) of the node's 96-dim row.

__global__ void deg_kernel(const int* __restrict__ col, int* __restrict__ deg, int E) {
    int e = blockIdx.x * blockDim.x + threadIdx.x;
    if (e < E) atomicAdd(&deg[col[e]], 1);
}

__global__ void deginv_kernel(const int* __restrict__ deg, float* __restrict__ deginv, int n) {
    int i = blockIdx.x * blockDim.x + threadIdx.x;
    if (i < n) {
        int d = deg[i];
        deginv[i] = (d > 0) ? rsqrtf((float)d) : 0.0f;
    }
}

// ---- hierarchical exclusive scan: 1024 elems/block ----
__global__ __launch_bounds__(256) void scan1_kernel(const int* __restrict__ deg,
                                                    int* __restrict__ starts,
                                                    int* __restrict__ bsums, int n) {
    int t = threadIdx.x;
    int i = blockIdx.x * 1024 + t * 4;
    int4 v = make_int4(0, 0, 0, 0);
    if (i + 3 < n) v = *(const int4*)(deg + i);
    else {
        if (i + 0 < n) v.x = deg[i + 0];
        if (i + 1 < n) v.y = deg[i + 1];
        if (i + 2 < n) v.z = deg[i + 2];
        if (i + 3 < n) v.w = deg[i + 3];
    }
    int s0 = v.x, s1 = s0 + v.y, s2 = s1 + v.z, s3 = s2 + v.w;
    int tot = s3;
    int lane = t & 63;
    int incl = tot;
    for (int off = 1; off < 64; off <<= 1) {
        int u = __shfl_up(incl, off, 64);
        if (lane >= off) incl += u;
    }
    __shared__ int wsum[4];
    __shared__ int woff[4];
    int wid = t >> 6;
    if (lane == 63) wsum[wid] = incl;
    __syncthreads();
    if (t == 0) { int a = 0; for (int w = 0; w < 4; ++w) { woff[w] = a; a += wsum[w]; } }
    __syncthreads();
    int excl = incl - tot + woff[wid];
    if (i + 0 < n) starts[i + 0] = excl;
    if (i + 1 < n) starts[i + 1] = excl + s0;
    if (i + 2 < n) starts[i + 2] = excl + s1;
    if (i + 3 < n) starts[i + 3] = excl + s2;
    if (t == 255) bsums[blockIdx.x] = woff[3] + wsum[3];
}

__global__ __launch_bounds__(64) void scan2_kernel(int* __restrict__ bsums, int nb,
                                                   int* __restrict__ starts, int n, int total) {
    int lane = threadIdx.x;
    int v = (lane < nb) ? bsums[lane] : 0;
    int incl = v;
    for (int off = 1; off < 64; off <<= 1) {
        int u = __shfl_up(incl, off, 64);
        if (lane >= off) incl += u;
    }
    if (lane < nb) bsums[lane] = incl - v;
    if (lane == 0) starts[n] = total;
}

__global__ __launch_bounds__(256) void scan3_kernel(int* __restrict__ starts,
                                                    int* __restrict__ cursor,
                                                    const int* __restrict__ bsums, int n) {
    int t = threadIdx.x;
    int i = blockIdx.x * 1024 + t * 4;
    int off = bsums[blockIdx.x];
    for (int k = 0; k < 4; ++k) {
        int ii = i + k;
        if (ii < n) {
            int s = starts[ii] + off;
            starts[ii] = s;
            cursor[ii] = s;
        }
    }
}

__global__ void fill_kernel(const int* __restrict__ col, int* __restrict__ cursor,
                            int* __restrict__ eids, int E) {
    int e = blockIdx.x * blockDim.x + threadIdx.x;
    if (e < E) {
        int pos = atomicAdd(&cursor[col[e]], 1);
        eids[pos] = e;
    }
}

// edat[j] = (bitcast row[e], norm[e]) in CSR slot order
__global__ void slot_kernel(const int* __restrict__ eids, const int* __restrict__ row,
                            const int* __restrict__ col, const float* __restrict__ deginv,
                            float2* __restrict__ edat, int E) {
    int j = blockIdx.x * blockDim.x + threadIdx.x;
    if (j < E) {
        int e = eids[j];
        int r = row[e], c = col[e];
        float2 o;
        o.x = __int_as_float(r);
        o.y = deginv[r] * deginv[c];
        edat[j] = o;
    }
}

#define CH 24  // D/4 float4 chunks per node

// Fused: b = sum norm*ef; x1 = sum norm*x[row] + b; out = h0*x + h1*x1
__global__ __launch_bounds__(256) void hop1_kernel(const int* __restrict__ starts,
                                                   const float2* __restrict__ edat,
                                                   const int* __restrict__ eids,
                                                   const float4* __restrict__ ef4,
                                                   const float4* __restrict__ x4,
                                                   float4* __restrict__ bvec4,
                                                   float4* __restrict__ xnext4,
                                                   float4* __restrict__ out4,
                                                   const float* __restrict__ hopwise,
                                                   int NC) {
    int g = blockIdx.x * 256 + threadIdx.x;
    if (g >= NC) return;
    int node = g / CH;
    int c = g - node * CH;
    int s = starts[node], e_end = starts[node + 1];
    float4 ab = make_float4(0.f, 0.f, 0.f, 0.f);
    float4 ax = make_float4(0.f, 0.f, 0.f, 0.f);
    int j = s;
    for (; j + 2 <= e_end; j += 2) {
        float2 a0 = edat[j], a1 = edat[j + 1];
        int e0 = eids[j], e1 = eids[j + 1];
        int r0 = __float_as_int(a0.x), r1 = __float_as_int(a1.x);
        float4 f0 = ef4[(size_t)e0 * CH + c];
        float4 f1 = ef4[(size_t)e1 * CH + c];
        float4 v0 = x4[(size_t)r0 * CH + c];
        float4 v1 = x4[(size_t)r1 * CH + c];
        ab.x += a0.y * f0.x + a1.y * f1.x;
        ab.y += a0.y * f0.y + a1.y * f1.y;
        ab.z += a0.y * f0.z + a1.y * f1.z;
        ab.w += a0.y * f0.w + a1.y * f1.w;
        ax.x += a0.y * v0.x + a1.y * v1.x;
        ax.y += a0.y * v0.y + a1.y * v1.y;
        ax.z += a0.y * v0.z + a1.y * v1.z;
        ax.w += a0.y * v0.w + a1.y * v1.w;
    }
    for (; j < e_end; ++j) {
        float2 a = edat[j];
        int e = eids[j];
        int r = __float_as_int(a.x);
        float4 f = ef4[(size_t)e * CH + c];
        float4 v = x4[(size_t)r * CH + c];
        ab.x += a.y * f.x; ab.y += a.y * f.y; ab.z += a.y * f.z; ab.w += a.y * f.w;
        ax.x += a.y * v.x; ax.y += a.y * v.y; ax.z += a.y * v.z; ax.w += a.y * v.w;
    }
    float h0 = hopwise[0], h1 = hopwise[1];
    size_t o = (size_t)node * CH + c;
    float4 xself = x4[o];
    float4 x1;
    x1.x = ax.x + ab.x; x1.y = ax.y + ab.y; x1.z = ax.z + ab.z; x1.w = ax.w + ab.w;
    bvec4[o] = ab;
    xnext4[o] = x1;
    float4 ov;
    ov.x = h0 * xself.x + h1 * x1.x;
    ov.y = h0 * xself.y + h1 * x1.y;
    ov.z = h0 * xself.z + h1 * x1.z;
    ov.w = h0 * xself.w + h1 * x1.w;
    out4[o] = ov;
}

// hops 2..K: xk = S*x_{k-1} + b; out += hk*xk
__global__ __launch_bounds__(256) void hop_kernel(const int* __restrict__ starts,
                                                  const float2* __restrict__ edat,
                                                  const float4* __restrict__ xcur4,
                                                  const float4* __restrict__ bvec4,
                                                  float4* __restrict__ xnext4,
                                                  float4* __restrict__ out4,
                                                  const float* __restrict__ hopwise,
                                                  int hop, int NC) {
    int g = blockIdx.x * 256 + threadIdx.x;
    if (g >= NC) return;
    int node = g / CH;
    int c = g - node * CH;
    int s = starts[node], e_end = starts[node + 1];
    float4 ax = make_float4(0.f, 0.f, 0.f, 0.f);
    int j = s;
    for (; j + 4 <= e_end; j += 4) {
        float2 a0 = edat[j], a1 = edat[j + 1], a2 = edat[j + 2], a3 = edat[j + 3];
        int r0 = __float_as_int(a0.x), r1 = __float_as_int(a1.x);
        int r2 = __float_as_int(a2.x), r3 = __float_as_int(a3.x);
        float4 v0 = xcur4[(size_t)r0 * CH + c];
        float4 v1 = xcur4[(size_t)r1 * CH + c];
        float4 v2 = xcur4[(size_t)r2 * CH + c];
        float4 v3 = xcur4[(size_t)r3 * CH + c];
        ax.x += a0.y * v0.x + a1.y * v1.x + a2.y * v2.x + a3.y * v3.x;
        ax.y += a0.y * v0.y + a1.y * v1.y + a2.y * v2.y + a3.y * v3.y;
        ax.z += a0.y * v0.z + a1.y * v1.z + a2.y * v2.z + a3.y * v3.z;
        ax.w += a0.y * v0.w + a1.y * v1.w + a2.y * v2.w + a3.y * v3.w;
    }
    for (; j < e_end; ++j) {
        float2 a = edat[j];
        int r = __float_as_int(a.x);
        float4 v = xcur4[(size_t)r * CH + c];
        ax.x += a.y * v.x; ax.y += a.y * v.y; ax.z += a.y * v.z; ax.w += a.y * v.w;
    }
    float h = hopwise[hop];
    size_t o = (size_t)node * CH + c;
    float4 b = bvec4[o];
    float4 xv;
    xv.x = ax.x + b.x; xv.y = ax.y + b.y; xv.z = ax.z + b.z; xv.w = ax.w + b.w;
    xnext4[o] = xv;
    float4 ov = out4[o];
    ov.x += h * xv.x; ov.y += h * xv.y; ov.z += h * xv.z; ov.w += h * xv.w;
    out4[o] = ov;
}

extern "C" void kernel_launch(void* const* d_in, const int* in_sizes, int n_in,
                              void* d_out, int out_size, void* d_ws, size_t ws_size,
                              hipStream_t stream) {
    const float* x       = (const float*)d_in[0];
    const float* ef      = (const float*)d_in[1];
    const float* hopwise = (const float*)d_in[2];
    const int*   eidx    = (const int*)d_in[3];

    const int E = in_sizes[3] / 2;
    const int D = in_sizes[1] / E;          // 96
    const int N = in_sizes[0] / D;          // 50000
    const int K = in_sizes[2] - 1;          // 3
    const int NC = N * (D / 4);             // node-chunks

    const int* row = eidx;
    const int* col = eidx + E;
    float* out = (float*)d_out;

    // Workspace layout (N even, E multiple of 4 -> 16B alignment holds)
    char* w = (char*)d_ws;
    int*    deg    = (int*)w;     w += (size_t)N * 4;
    int*    starts = (int*)w;     w += (size_t)(N + 8) * 4;
    int*    cursor = (int*)w;     w += (size_t)N * 4;
    int*    eids   = (int*)w;     w += (size_t)E * 4;
    float*  deginv = (float*)w;   w += (size_t)N * 4;
    int*    bsums  = (int*)w;     w += 256 * 4;
    float2* edat   = (float2*)w;  w += (size_t)E * 8;
    float*  bvec   = (float*)w;   w += (size_t)N * D * 4;
    float*  buf0   = (float*)w;   w += (size_t)N * D * 4;
    float*  buf1   = (float*)w;   /* w += N*D*4 */

    const int BT = 256;
    const int nScanBlocks = (N + 1023) / 1024;

    // CSR build
    hipMemsetAsync(deg, 0, (size_t)N * sizeof(int), stream);
    deg_kernel<<<(E + BT - 1) / BT, BT, 0, stream>>>(col, deg, E);
    deginv_kernel<<<(N + BT - 1) / BT, BT, 0, stream>>>(deg, deginv, N);
    scan1_kernel<<<nScanBlocks, 256, 0, stream>>>(deg, starts, bsums, N);
    scan2_kernel<<<1, 64, 0, stream>>>(bsums, nScanBlocks, starts, N, E);
    scan3_kernel<<<nScanBlocks, 256, 0, stream>>>(starts, cursor, bsums, N);
    fill_kernel<<<(E + BT - 1) / BT, BT, 0, stream>>>(col, cursor, eids, E);
    slot_kernel<<<(E + BT - 1) / BT, BT, 0, stream>>>(eids, row, col, deginv, edat, E);

    // Fused hop 1 (+ b computation + out init)
    int hopBlocks = (NC + 255) / 256;
    hop1_kernel<<<hopBlocks, 256, 0, stream>>>(starts, edat, eids, (const float4*)ef,
                                               (const float4*)x, (float4*)bvec,
                                               (float4*)buf0, (float4*)out, hopwise, NC);

    // hops 2..K
    const float* xcur = buf0;
    for (int hop = 2; hop <= K; ++hop) {
        float* xnext = (hop & 1) ? buf1 : buf0;
        if (xnext == xcur) xnext = (xcur == buf0) ? buf1 : buf0;
        hop_kernel<<<hopBlocks, 256, 0, stream>>>(starts, edat, (const float4*)xcur,
                                                  (const float4*)bvec, (float4*)xnext,
                                                  (float4*)out, hopwise, hop, NC);
        xcur = xnext;
    }
}